// Round 1
// baseline (185.003 us; speedup 1.0000x reference)
//
#include <hip/hip_runtime.h>
#include <math.h>

#define NB 8            // batch
#define NPIX 262144     // 512*512
#define NBINS 2048
#define TPB 256
#define BPS 32          // blocks per sample
#define PPB (NPIX / BPS)   // 8192 pixels per block
#define EPS2 1e-12f

struct SelState { unsigned b1; unsigned rem; float sum_gt; unsigned k; };

#define F4E(v,j) (((const float*)&(v))[j])
#define I4E(v,j) (((const int*)&(v))[j])

__device__ __forceinline__ void pixel_vals(float a, float p,
                                           float i0, float i1, float i2,
                                           float f0, float f1, float f2,
                                           float g0, float g1, float g2,
                                           float& d, float& dc)
{
    float diff = a * (1.0f / 255.0f) - p;
    d = sqrtf(diff * diff + EPS2);
    float om = 1.0f - p;
    float e0 = i0 - (f0 * p + om * g0);
    float e1 = i1 - (f1 * p + om * g1);
    float e2 = i2 - (f2 * p + om * g2);
    dc = sqrtf(e0 * e0 + EPS2) + sqrtf(e1 * e1 + EPS2) + sqrtf(e2 * e2 + EPS2);
}

// ---------------- Kernel A: compute values, count unknown, level-1 histogram ----------------
__global__ __launch_bounds__(TPB) void k_compute_hist1(
    const float* __restrict__ image, const float* __restrict__ alpha,
    const float* __restrict__ pred, const int* __restrict__ trimap,
    const float* __restrict__ fg, const float* __restrict__ bg,
    unsigned* __restrict__ gcnt, unsigned* __restrict__ h1c, float* __restrict__ h1s)
{
    __shared__ unsigned hc[2 * NBINS];
    __shared__ float    hs[2 * NBINS];
    const int tid = threadIdx.x;
    for (int i = tid; i < 2 * NBINS; i += TPB) { hc[i] = 0u; hs[i] = 0.f; }
    __syncthreads();

    const int s = blockIdx.x >> 5;
    const int chunk = blockIdx.x & 31;
    const int pbase = s * NPIX + chunk * PPB;
    const int cbase = s * 3 * NPIX + chunk * PPB;

    unsigned nUnk = 0, nMask = 0;

    for (int it = 0; it < PPB / (TPB * 4); ++it) {
        const int off = (it * TPB + tid) * 4;
        int4   tm = *(const int4*)(trimap + pbase + off);
        float4 al = *(const float4*)(alpha + pbase + off);
        float4 pr = *(const float4*)(pred + pbase + off);
        float4 i0 = *(const float4*)(image + cbase + off);
        float4 i1 = *(const float4*)(image + cbase + NPIX + off);
        float4 i2 = *(const float4*)(image + cbase + 2 * NPIX + off);
        float4 f0 = *(const float4*)(fg + cbase + off);
        float4 f1 = *(const float4*)(fg + cbase + NPIX + off);
        float4 f2 = *(const float4*)(fg + cbase + 2 * NPIX + off);
        float4 g0 = *(const float4*)(bg + cbase + off);
        float4 g1 = *(const float4*)(bg + cbase + NPIX + off);
        float4 g2 = *(const float4*)(bg + cbase + 2 * NPIX + off);
#pragma unroll
        for (int j = 0; j < 4; ++j) {
            if (I4E(tm, j) == 128) {
                ++nUnk;
                float d, dc;
                pixel_vals(F4E(al, j), F4E(pr, j),
                           F4E(i0, j), F4E(i1, j), F4E(i2, j),
                           F4E(f0, j), F4E(f1, j), F4E(f2, j),
                           F4E(g0, j), F4E(g1, j), F4E(g2, j), d, dc);
                unsigned bd = __float_as_uint(d) >> 21;
                atomicAdd(&hc[bd], 1u); atomicAdd(&hs[bd], d);
                unsigned bc = NBINS + (__float_as_uint(dc) >> 21);
                atomicAdd(&hc[bc], 1u); atomicAdd(&hs[bc], dc);
            } else {
                ++nMask;
            }
        }
    }

    // reduce per-thread counters: wave shuffle then LDS
    unsigned u = nUnk, m = nMask;
#pragma unroll
    for (int o = 32; o > 0; o >>= 1) { u += __shfl_down(u, o); m += __shfl_down(m, o); }
    __shared__ unsigned wred[8];
    const int wave = tid >> 6;
    if ((tid & 63) == 0) { wred[wave * 2] = u; wred[wave * 2 + 1] = m; }
    __syncthreads();
    if (tid == 0) {
        unsigned U = 0, M = 0;
        for (int w = 0; w < 4; ++w) { U += wred[w * 2]; M += wred[w * 2 + 1]; }
        atomicAdd(&gcnt[s], U);
        const float md  = sqrtf(EPS2);
        const float mdc = md + md + md;
        if (M) {
            unsigned bd = __float_as_uint(md) >> 21;
            unsigned bc = NBINS + (__float_as_uint(mdc) >> 21);
            atomicAdd(&hc[bd], M); atomicAdd(&hs[bd], (float)M * md);
            atomicAdd(&hc[bc], M); atomicAdd(&hs[bc], (float)M * mdc);
        }
    }
    __syncthreads();

    for (int i = tid; i < 2 * NBINS; i += TPB) {
        unsigned c = hc[i];
        if (c) {
            int arr = (i >= NBINS) ? 1 : 0;
            int b = i & (NBINS - 1);
            int o = (s * 2 + arr) * NBINS + b;
            atomicAdd(&h1c[o], c);
            atomicAdd(&h1s[o], hs[i]);
        }
    }
}

// ---------------- Kernel B: level-1 selection ----------------
__global__ __launch_bounds__(TPB) void k_select1(
    const unsigned* __restrict__ gcnt, const unsigned* __restrict__ h1c,
    const float* __restrict__ h1s, SelState* __restrict__ st)
{
    const int unit = blockIdx.x;
    const int s = unit >> 1;
    const int t = threadIdx.x;
    const unsigned* hc = h1c + unit * NBINS;
    const float*    hm = h1s + unit * NBINS;
    unsigned count = gcnt[s];
    int k = (int)floorf((float)count * 0.7f);

    __shared__ unsigned spc[TPB]; __shared__ float sps[TPB];
    unsigned pc = 0; float ps = 0.f;
#pragma unroll
    for (int j = 0; j < NBINS / TPB; ++j) { pc += hc[t * (NBINS / TPB) + j]; ps += hm[t * (NBINS / TPB) + j]; }
    spc[t] = pc; sps[t] = ps;
    __syncthreads();
    __shared__ unsigned sufc[TPB + 1]; __shared__ float sufs[TPB + 1];
    if (t == 0) {
        unsigned c = 0; float sm = 0.f;
        sufc[TPB] = 0; sufs[TPB] = 0.f;
        for (int i = TPB - 1; i >= 0; --i) { c += spc[i]; sm += sps[i]; sufc[i] = c; sufs[i] = sm; }
    }
    __syncthreads();
    if (k <= 0) {
        if (t == 0) { st[unit].b1 = 0xFFFFFFFFu; st[unit].rem = 0; st[unit].sum_gt = 0.f; st[unit].k = 0; }
        return;
    }
    unsigned above = sufc[t + 1];
    if (above < (unsigned)k && (unsigned)k <= sufc[t]) {
        unsigned c = above; float sm = sufs[t + 1];
        int b1 = t * (NBINS / TPB);
        for (int j = NBINS / TPB - 1; j >= 0; --j) {
            unsigned bcn = hc[t * (NBINS / TPB) + j];
            if (c + bcn >= (unsigned)k) { b1 = t * (NBINS / TPB) + j; break; }
            c += bcn; sm += hm[t * (NBINS / TPB) + j];
        }
        st[unit].b1 = (unsigned)b1;
        st[unit].rem = (unsigned)k - c;
        st[unit].sum_gt = sm;
        st[unit].k = (unsigned)k;
    }
}

// ---------------- Kernel C: level-2 histogram (recompute values) ----------------
__global__ __launch_bounds__(TPB) void k_hist2(
    const float* __restrict__ image, const float* __restrict__ alpha,
    const float* __restrict__ pred, const int* __restrict__ trimap,
    const float* __restrict__ fg, const float* __restrict__ bg,
    const SelState* __restrict__ st, unsigned* __restrict__ h2c, float* __restrict__ h2s)
{
    const int s = blockIdx.x >> 5;
    const int chunk = blockIdx.x & 31;
    const unsigned b1d = st[s * 2 + 0].b1;
    const unsigned b1c = st[s * 2 + 1].b1;
    const int pbase = s * NPIX + chunk * PPB;
    const int cbase = s * 3 * NPIX + chunk * PPB;
    unsigned* h2cd = h2c + (s * 2 + 0) * NBINS;
    float*    h2sd = h2s + (s * 2 + 0) * NBINS;
    unsigned* h2cc = h2c + (s * 2 + 1) * NBINS;
    float*    h2sc = h2s + (s * 2 + 1) * NBINS;
    const int tid = threadIdx.x;
    unsigned nMask = 0;

    for (int it = 0; it < PPB / (TPB * 4); ++it) {
        const int off = (it * TPB + tid) * 4;
        int4   tm = *(const int4*)(trimap + pbase + off);
        float4 al = *(const float4*)(alpha + pbase + off);
        float4 pr = *(const float4*)(pred + pbase + off);
        float4 i0 = *(const float4*)(image + cbase + off);
        float4 i1 = *(const float4*)(image + cbase + NPIX + off);
        float4 i2 = *(const float4*)(image + cbase + 2 * NPIX + off);
        float4 f0 = *(const float4*)(fg + cbase + off);
        float4 f1 = *(const float4*)(fg + cbase + NPIX + off);
        float4 f2 = *(const float4*)(fg + cbase + 2 * NPIX + off);
        float4 g0 = *(const float4*)(bg + cbase + off);
        float4 g1 = *(const float4*)(bg + cbase + NPIX + off);
        float4 g2 = *(const float4*)(bg + cbase + 2 * NPIX + off);
#pragma unroll
        for (int j = 0; j < 4; ++j) {
            if (I4E(tm, j) == 128) {
                float d, dc;
                pixel_vals(F4E(al, j), F4E(pr, j),
                           F4E(i0, j), F4E(i1, j), F4E(i2, j),
                           F4E(f0, j), F4E(f1, j), F4E(f2, j),
                           F4E(g0, j), F4E(g1, j), F4E(g2, j), d, dc);
                unsigned bits = __float_as_uint(d);
                if ((bits >> 21) == b1d) {
                    unsigned sb = (bits >> 10) & (NBINS - 1);
                    atomicAdd(&h2cd[sb], 1u); atomicAdd(&h2sd[sb], d);
                }
                unsigned bits2 = __float_as_uint(dc);
                if ((bits2 >> 21) == b1c) {
                    unsigned sb = (bits2 >> 10) & (NBINS - 1);
                    atomicAdd(&h2cc[sb], 1u); atomicAdd(&h2sc[sb], dc);
                }
            } else {
                ++nMask;
            }
        }
    }

    unsigned m = nMask;
#pragma unroll
    for (int o = 32; o > 0; o >>= 1) { m += __shfl_down(m, o); }
    __shared__ unsigned wred[4];
    const int wave = tid >> 6;
    if ((tid & 63) == 0) { wred[wave] = m; }
    __syncthreads();
    if (tid == 0) {
        unsigned M = 0;
        for (int w = 0; w < 4; ++w) M += wred[w];
        if (M) {
            const float md  = sqrtf(EPS2);
            const float mdc = md + md + md;
            unsigned bmd  = __float_as_uint(md);
            unsigned bmdc = __float_as_uint(mdc);
            if ((bmd >> 21) == b1d) {
                unsigned sb = (bmd >> 10) & (NBINS - 1);
                atomicAdd(&h2cd[sb], M); atomicAdd(&h2sd[sb], (float)M * md);
            }
            if ((bmdc >> 21) == b1c) {
                unsigned sb = (bmdc >> 10) & (NBINS - 1);
                atomicAdd(&h2cc[sb], M); atomicAdd(&h2sc[sb], (float)M * mdc);
            }
        }
    }
}

// ---------------- Kernel D: level-2 selection + per-unit loss ----------------
__global__ __launch_bounds__(TPB) void k_select2(
    const unsigned* __restrict__ h2c, const float* __restrict__ h2s,
    const SelState* __restrict__ st, float* __restrict__ loss)
{
    const int unit = blockIdx.x;
    const int t = threadIdx.x;
    SelState S = st[unit];
    if (S.b1 == 0xFFFFFFFFu) { if (t == 0) loss[unit] = 0.f; return; }
    const unsigned* hc = h2c + unit * NBINS;
    const float*    hm = h2s + unit * NBINS;

    __shared__ unsigned spc[TPB]; __shared__ float sps[TPB];
    unsigned pc = 0; float ps = 0.f;
#pragma unroll
    for (int j = 0; j < NBINS / TPB; ++j) { pc += hc[t * (NBINS / TPB) + j]; ps += hm[t * (NBINS / TPB) + j]; }
    spc[t] = pc; sps[t] = ps;
    __syncthreads();
    __shared__ unsigned sufc[TPB + 1]; __shared__ float sufs[TPB + 1];
    if (t == 0) {
        unsigned c = 0; float sm = 0.f;
        sufc[TPB] = 0; sufs[TPB] = 0.f;
        for (int i = TPB - 1; i >= 0; --i) { c += spc[i]; sm += sps[i]; sufc[i] = c; sufs[i] = sm; }
    }
    __syncthreads();
    unsigned k = S.rem;
    unsigned above = sufc[t + 1];
    if (above < k && k <= sufc[t]) {
        unsigned c = above; float sm = sufs[t + 1];
        unsigned bcn = 0; float bsm = 0.f;
        for (int j = NBINS / TPB - 1; j >= 0; --j) {
            bcn = hc[t * (NBINS / TPB) + j]; bsm = hm[t * (NBINS / TPB) + j];
            if (c + bcn >= k) break;
            c += bcn; sm += bsm;
        }
        unsigned rem2 = k - c;
        float avg = bsm / (float)bcn;
        float sum_k = S.sum_gt + sm + (float)rem2 * avg;
        loss[unit] = sum_k / ((float)S.k + 1e-6f);
    }
}

// ---------------- Kernel E: final combine ----------------
__global__ void k_final(const float* __restrict__ loss, float* __restrict__ out)
{
    if (threadIdx.x == 0 && blockIdx.x == 0) {
        float acc = 0.f;
        for (int s = 0; s < NB; ++s) acc += 0.5f * loss[2 * s + 0] + 0.5f * loss[2 * s + 1];
        out[0] = acc * (1.0f / NB);
    }
}

extern "C" void kernel_launch(void* const* d_in, const int* in_sizes, int n_in,
                              void* d_out, int out_size, void* d_ws, size_t ws_size,
                              hipStream_t stream)
{
    const float* image  = (const float*)d_in[0];
    const float* alpha  = (const float*)d_in[1];
    const float* pred   = (const float*)d_in[2];
    const int*   trimap = (const int*)d_in[3];
    const float* fg     = (const float*)d_in[4];
    const float* bg     = (const float*)d_in[5];
    float* out = (float*)d_out;

    char* ws = (char*)d_ws;
    // layout: gcnt[8] | h1c | h1s | h2c | h2s | SelState[16] | loss[16]
    unsigned* gcnt = (unsigned*)(ws);
    unsigned* h1c  = (unsigned*)(ws + 64);
    float*    h1s  = (float*)(ws + 64 + 1 * 131072);
    unsigned* h2c  = (unsigned*)(ws + 64 + 2 * 131072);
    float*    h2s  = (float*)(ws + 64 + 3 * 131072);
    SelState* st   = (SelState*)(ws + 64 + 4 * 131072);
    float*    loss = (float*)(ws + 64 + 4 * 131072 + 256);
    size_t zbytes = 64 + 4 * 131072 + 256 + 64;

    hipMemsetAsync(d_ws, 0, zbytes, stream);
    k_compute_hist1<<<NB * BPS, TPB, 0, stream>>>(image, alpha, pred, trimap, fg, bg, gcnt, h1c, h1s);
    k_select1<<<NB * 2, TPB, 0, stream>>>(gcnt, h1c, h1s, st);
    k_hist2<<<NB * BPS, TPB, 0, stream>>>(image, alpha, pred, trimap, fg, bg, st, h2c, h2s);
    k_select2<<<NB * 2, TPB, 0, stream>>>(h2c, h2s, st, loss);
    k_final<<<1, 64, 0, stream>>>(loss, out);
}

// Round 2
// 170.278 us; speedup vs baseline: 1.0865x; 1.0865x over previous
//
#include <hip/hip_runtime.h>
#include <math.h>

#define NB 8            // batch
#define NPIX 262144     // 512*512
#define NBINS 2048
#define TPB 256
#define BPS 64          // blocks per sample (pass 1)
#define PPB (NPIX / BPS)   // 4096 pixels per block
#define EPS2 1e-12f

struct SelState { unsigned b1; unsigned rem; unsigned k; unsigned pad; };

#define F4E(v,j) (((const float*)&(v))[j])
#define I4E(v,j) (((const int*)&(v))[j])

__device__ __forceinline__ void pixel_vals(float a, float p,
                                           float i0, float i1, float i2,
                                           float f0, float f1, float f2,
                                           float g0, float g1, float g2,
                                           float& d, float& dc)
{
    float diff = a * (1.0f / 255.0f) - p;
    d = sqrtf(diff * diff + EPS2);
    float om = 1.0f - p;
    float e0 = i0 - (f0 * p + om * g0);
    float e1 = i1 - (f1 * p + om * g1);
    float e2 = i2 - (f2 * p + om * g2);
    dc = sqrtf(e0 * e0 + EPS2) + sqrtf(e1 * e1 + EPS2) + sqrtf(e2 * e2 + EPS2);
}

// ---------------- Pass 1: compute values, store them, count-only level-1 histogram ----------------
__global__ __launch_bounds__(TPB) void k_pass1(
    const float* __restrict__ image, const float* __restrict__ alpha,
    const float* __restrict__ pred, const int* __restrict__ trimap,
    const float* __restrict__ fg, const float* __restrict__ bg,
    unsigned* __restrict__ gcnt, unsigned* __restrict__ h1c, float* __restrict__ vals)
{
    __shared__ unsigned hc[2 * NBINS];   // counts only: [0..NBINS) = d, [NBINS..2N) = dc
    const int tid = threadIdx.x;
    for (int i = tid; i < 2 * NBINS; i += TPB) hc[i] = 0u;
    __syncthreads();

    const int s = blockIdx.x / BPS;
    const int chunk = blockIdx.x % BPS;
    const int pbase = s * NPIX + chunk * PPB;
    const int cbase = s * 3 * NPIX + chunk * PPB;
    // unit-major value layout: unit = s*2 + {0:d, 1:dc}
    float* vd = vals + (s * 2 + 0) * NPIX + chunk * PPB;
    float* vc = vals + (s * 2 + 1) * NPIX + chunk * PPB;

    const float md  = sqrtf(EPS2);        // masked-pixel d value
    const float mdc = md + md + md;       // masked-pixel dc value

    unsigned nUnk = 0, nMask = 0;

    for (int it = 0; it < PPB / (TPB * 4); ++it) {
        const int off = (it * TPB + tid) * 4;
        int4   tm = *(const int4*)(trimap + pbase + off);
        float4 al = *(const float4*)(alpha + pbase + off);
        float4 pr = *(const float4*)(pred + pbase + off);
        float4 i0 = *(const float4*)(image + cbase + off);
        float4 i1 = *(const float4*)(image + cbase + NPIX + off);
        float4 i2 = *(const float4*)(image + cbase + 2 * NPIX + off);
        float4 f0 = *(const float4*)(fg + cbase + off);
        float4 f1 = *(const float4*)(fg + cbase + NPIX + off);
        float4 f2 = *(const float4*)(fg + cbase + 2 * NPIX + off);
        float4 g0 = *(const float4*)(bg + cbase + off);
        float4 g1 = *(const float4*)(bg + cbase + NPIX + off);
        float4 g2 = *(const float4*)(bg + cbase + 2 * NPIX + off);
        float4 od, oc;
#pragma unroll
        for (int j = 0; j < 4; ++j) {
            float d, dc;
            if (I4E(tm, j) == 128) {
                ++nUnk;
                pixel_vals(F4E(al, j), F4E(pr, j),
                           F4E(i0, j), F4E(i1, j), F4E(i2, j),
                           F4E(f0, j), F4E(f1, j), F4E(f2, j),
                           F4E(g0, j), F4E(g1, j), F4E(g2, j), d, dc);
                atomicAdd(&hc[__float_as_uint(d) >> 21], 1u);
                atomicAdd(&hc[NBINS + (__float_as_uint(dc) >> 21)], 1u);
            } else {
                ++nMask;
                d = md; dc = mdc;
            }
            ((float*)&od)[j] = d;
            ((float*)&oc)[j] = dc;
        }
        *(float4*)(vd + off) = od;
        *(float4*)(vc + off) = oc;
    }

    // reduce per-thread counters: wave shuffle then LDS
    unsigned u = nUnk, m = nMask;
#pragma unroll
    for (int o = 32; o > 0; o >>= 1) { u += __shfl_down(u, o); m += __shfl_down(m, o); }
    __shared__ unsigned wred[8];
    const int wave = tid >> 6;
    if ((tid & 63) == 0) { wred[wave * 2] = u; wred[wave * 2 + 1] = m; }
    __syncthreads();
    if (tid == 0) {
        unsigned U = 0, M = 0;
        for (int w = 0; w < 4; ++w) { U += wred[w * 2]; M += wred[w * 2 + 1]; }
        atomicAdd(&gcnt[s], U);
        if (M) {  // all masked pixels hit one known bin per array: one aggregated update
            atomicAdd(&hc[__float_as_uint(md) >> 21], M);
            atomicAdd(&hc[NBINS + (__float_as_uint(mdc) >> 21)], M);
        }
    }
    __syncthreads();

    for (int i = tid; i < 2 * NBINS; i += TPB) {
        unsigned c = hc[i];
        if (c) {
            int arr = (i >= NBINS) ? 1 : 0;
            int b = i & (NBINS - 1);
            atomicAdd(&h1c[(s * 2 + arr) * NBINS + b], c);
        }
    }
}

// ---------------- Level-1 selection (counts only) ----------------
__global__ __launch_bounds__(TPB) void k_select1(
    const unsigned* __restrict__ gcnt, const unsigned* __restrict__ h1c,
    SelState* __restrict__ st)
{
    const int unit = blockIdx.x;
    const int s = unit >> 1;
    const int t = threadIdx.x;
    const unsigned* hc = h1c + unit * NBINS;
    unsigned count = gcnt[s];
    int k = (int)floorf((float)count * 0.7f);

    __shared__ unsigned spc[TPB];
    unsigned pc = 0;
#pragma unroll
    for (int j = 0; j < NBINS / TPB; ++j) pc += hc[t * (NBINS / TPB) + j];
    spc[t] = pc;
    __syncthreads();
    __shared__ unsigned sufc[TPB + 1];
    if (t == 0) {
        unsigned c = 0;
        sufc[TPB] = 0;
        for (int i = TPB - 1; i >= 0; --i) { c += spc[i]; sufc[i] = c; }
    }
    __syncthreads();
    if (k <= 0) {
        if (t == 0) { st[unit].b1 = 0xFFFFFFFFu; st[unit].rem = 0; st[unit].k = 0; }
        return;
    }
    unsigned above = sufc[t + 1];
    if (above < (unsigned)k && (unsigned)k <= sufc[t]) {
        unsigned c = above;
        int b1 = t * (NBINS / TPB);
        for (int j = NBINS / TPB - 1; j >= 0; --j) {
            unsigned bcn = hc[t * (NBINS / TPB) + j];
            if (c + bcn >= (unsigned)k) { b1 = t * (NBINS / TPB) + j; break; }
            c += bcn;
        }
        st[unit].b1 = (unsigned)b1;
        st[unit].rem = (unsigned)k - c;   // >= 1
        st[unit].k = (unsigned)k;
    }
}

// ---------------- Pass 2: read stored values; sum above b1; level-2 hist for bin == b1 ----------------
__global__ __launch_bounds__(TPB) void k_pass2(
    const float* __restrict__ vals, const SelState* __restrict__ st,
    unsigned* __restrict__ h2c, float* __restrict__ h2s, float* __restrict__ sumgt)
{
    const int unit = blockIdx.x >> 5;     // 32 blocks per unit
    const int chunk = blockIdx.x & 31;    // 8192 values per block
    const SelState S = st[unit];
    if (S.b1 == 0xFFFFFFFFu) return;
    const float* v = vals + unit * NPIX + chunk * 8192;
    unsigned* hcd = h2c + unit * NBINS;
    float*    hsd = h2s + unit * NBINS;
    const int tid = threadIdx.x;

    float lsum = 0.f;
    for (int it = 0; it < 8192 / (TPB * 4); ++it) {
        const int off = (it * TPB + tid) * 4;
        float4 x = *(const float4*)(v + off);
#pragma unroll
        for (int j = 0; j < 4; ++j) {
            float val = F4E(x, j);
            unsigned bits = __float_as_uint(val);
            unsigned b = bits >> 21;
            if (b > S.b1) {
                lsum += val;
            } else if (b == S.b1) {
                unsigned sb = (bits >> 10) & (NBINS - 1);
                atomicAdd(&hcd[sb], 1u);
                atomicAdd(&hsd[sb], val);
            }
        }
    }
    // block-reduce lsum
#pragma unroll
    for (int o = 32; o > 0; o >>= 1) lsum += __shfl_down(lsum, o);
    __shared__ float wred[4];
    const int wave = tid >> 6;
    if ((tid & 63) == 0) wred[wave] = lsum;
    __syncthreads();
    if (tid == 0) {
        float tot = wred[0] + wred[1] + wred[2] + wred[3];
        atomicAdd(&sumgt[unit], tot);
    }
}

// ---------------- Level-2 selection + final combine (atomic into zeroed d_out) ----------------
__global__ __launch_bounds__(TPB) void k_select2_final(
    const unsigned* __restrict__ h2c, const float* __restrict__ h2s,
    const SelState* __restrict__ st, const float* __restrict__ sumgt,
    float* __restrict__ out)
{
    const int unit = blockIdx.x;
    const int t = threadIdx.x;
    SelState S = st[unit];
    if (S.b1 == 0xFFFFFFFFu) return;   // k==0 contributes 0
    const unsigned* hc = h2c + unit * NBINS;
    const float*    hm = h2s + unit * NBINS;

    __shared__ unsigned spc[TPB]; __shared__ float sps[TPB];
    unsigned pc = 0; float ps = 0.f;
#pragma unroll
    for (int j = 0; j < NBINS / TPB; ++j) { pc += hc[t * (NBINS / TPB) + j]; ps += hm[t * (NBINS / TPB) + j]; }
    spc[t] = pc; sps[t] = ps;
    __syncthreads();
    __shared__ unsigned sufc[TPB + 1]; __shared__ float sufs[TPB + 1];
    if (t == 0) {
        unsigned c = 0; float sm = 0.f;
        sufc[TPB] = 0; sufs[TPB] = 0.f;
        for (int i = TPB - 1; i >= 0; --i) { c += spc[i]; sm += sps[i]; sufc[i] = c; sufs[i] = sm; }
    }
    __syncthreads();
    unsigned k = S.rem;                // >= 1, guaranteed a crossing exists
    unsigned above = sufc[t + 1];
    if (above < k && k <= sufc[t]) {
        unsigned c = above; float sm = sufs[t + 1];
        unsigned bcn = 0; float bsm = 0.f;
        for (int j = NBINS / TPB - 1; j >= 0; --j) {
            bcn = hc[t * (NBINS / TPB) + j]; bsm = hm[t * (NBINS / TPB) + j];
            if (c + bcn >= k) break;
            c += bcn; sm += bsm;
        }
        unsigned rem2 = k - c;
        float avg = bsm / (float)bcn;  // bin width 2^-13 relative -> negligible error
        float sum_k = sumgt[unit] + sm + (float)rem2 * avg;
        float loss = sum_k / ((float)S.k + 1e-6f);
        atomicAdd(out, 0.0625f * loss);   // 0.5 stage weight / 8 samples, both arrays
    }
}

extern "C" void kernel_launch(void* const* d_in, const int* in_sizes, int n_in,
                              void* d_out, int out_size, void* d_ws, size_t ws_size,
                              hipStream_t stream)
{
    const float* image  = (const float*)d_in[0];
    const float* alpha  = (const float*)d_in[1];
    const float* pred   = (const float*)d_in[2];
    const int*   trimap = (const int*)d_in[3];
    const float* fg     = (const float*)d_in[4];
    const float* bg     = (const float*)d_in[5];
    float* out = (float*)d_out;

    char* ws = (char*)d_ws;
    // layout: gcnt[8](64B) | h1c 128KB | h2c 128KB | h2s 128KB | sumgt[16](64B) | st[16](256B) | vals 16MB
    unsigned* gcnt = (unsigned*)(ws);
    unsigned* h1c  = (unsigned*)(ws + 64);
    unsigned* h2c  = (unsigned*)(ws + 64 + 1 * 131072);
    float*    h2s  = (float*)(ws + 64 + 2 * 131072);
    float*    sumgt= (float*)(ws + 64 + 3 * 131072);
    SelState* st   = (SelState*)(ws + 64 + 3 * 131072 + 64);
    float*    vals = (float*)(ws + 409600);
    const size_t zbytes = 64 + 3 * 131072 + 64;   // gcnt..sumgt

    hipMemsetAsync(d_ws, 0, zbytes, stream);
    hipMemsetAsync(d_out, 0, sizeof(float), stream);
    k_pass1<<<NB * BPS, TPB, 0, stream>>>(image, alpha, pred, trimap, fg, bg, gcnt, h1c, vals);
    k_select1<<<NB * 2, TPB, 0, stream>>>(gcnt, h1c, st);
    k_pass2<<<16 * 32, TPB, 0, stream>>>(vals, st, h2c, h2s, sumgt);
    k_select2_final<<<16, TPB, 0, stream>>>(h2c, h2s, st, sumgt, out);
}